// Round 15
// baseline (286.288 us; speedup 1.0000x reference)
//
#include <hip/hip_runtime.h>

// ExpansionContrastModule on MI355X (gfx950), bf16 MFMA pipeline.
// R7 associativity: out = (ws·VW)·surr - (wc·LW)·cen (deletes 137-GF vals GEMM).
// R9 determinism: no atomics; single-writer partial slots everywhere.
// R10: G5 split-K x4 planes. R11: T1 XCD swizzle on G1/G6n. R12: gather
// address hoisting. R13: G3/G7 64x128 retile, 1024-thr softmax.
// R14 kept: G1 512-thr 8-wave blocks (2Mx4N, 16 waves/CU) -> 905 TF, at the
// verified 2-phase structure ceiling (m97: 912 TF).
// R15: prep fusion REVERTED to r13's split kernels (cast_all + 3x
// transpose_cast) — r14's prep_all carried the transpose branch's LDS/reg
// footprint on all 4177 blocks and cost ~9us in the tail.

typedef unsigned short u16;
typedef unsigned int u32;
typedef __attribute__((ext_vector_type(4))) unsigned int u32x4;
typedef __attribute__((ext_vector_type(8))) short s16x8;
typedef __attribute__((ext_vector_type(4))) float f32x4;

#define DEVFN static __device__ __forceinline__

DEVFN u16 f2bf(float f) {
    u32 u = __builtin_bit_cast(u32, f);
    u32 r = (u + 0x7fffu + ((u >> 16) & 1u)) >> 16;  // RNE
    return (u16)r;
}
DEVFN float bf2f(u32 h) { u32 u = h << 16; return __builtin_bit_cast(float, u); }

typedef __attribute__((address_space(1))) const unsigned int gu32;
typedef __attribute__((address_space(3))) unsigned int lu32;
DEVFN void gld16(const void* g, void* l) {
    __builtin_amdgcn_global_load_lds((gu32*)g, (lu32*)l, 16, 0, 0);
}

// OFFSETS = [(-1,-1),(-1,0),(-1,1),(0,1),(1,1),(1,0),(1,-1),(0,-1)]
__constant__ int cOFFY[8] = {-1,-1,-1, 0, 1, 1, 1, 0};
__constant__ int cOFFX[8] = {-1, 0, 1, 1, 1, 0,-1,-1};

// cenT row stride (4096 area rows + 1 zero row) in u16 elements
#define CENROWS 4097

// XOR swizzle within a 128B LDS row (BK=64 bf16): measured 0 conflicts (r1-r14).
DEVFN int swz(int r, int kb) { return r * 128 + (kb ^ ((r & 7) << 4)); }

// ---------------------------------------------------------------------------
// 2-phase TN GEMM. BK=64. THREADS=256 (4 waves, 2x2) or 512 (8 waves, 2x4).
// LDS = 2*(BM+BN)*128 B.
// XG/YG: operand gathered from cen_t; k<2048 -> offset j=k>>8 shifted by
// dilation, k>=2048 -> unshifted rows. Offsets precomputed per j (every 4
// K-tiles) into statically indexed registers; OOB -> cenT zero row (4096).
// DM: 0 = bf16 out, 1 = f32 out (plane ksl*kpl when KSP>1).
// NRM (deterministic single-writer partials):
//  1 = per-row ||row||^2 (bf16-rounded) -> nrm[(rowid<<NSH) + by*NWN + widN]
//  2 = per-row (sum,sumsq) -> nrm[row*256 + b*64 + by*2 + (wid&1)], +65536.
// KSP: split-K count; by = ytile*KSP + kslice; deterministic output planes.
// SWZ: T1 XCD-chunked remap (requires nwg % 8 == 0).
// ---------------------------------------------------------------------------
template<int BM, int BN, int WRM, int WRN, int XG, int YG, int DM, int NRM,
         int KSP, int SWZ, int THREADS, int NSH>
__global__ __launch_bounds__(THREADS, (THREADS == 512 ? 4 : 2))
void gemm_tn(const u16* __restrict__ X, const u16* __restrict__ Y,
             void* __restrict__ D, const u16* __restrict__ cenT,
             float* __restrict__ nrm,
             int K, int ldx, int ldy, int ldd, int sbits,
             long xb, long xs, long yb, long ys, long db, long dsn,
             long nb, long ns, long kpl)
{
    static_assert(KSP == 1 || (!XG && !YG), "split-K only for non-gather");
    constexpr int NWN = (THREADS == 512) ? 4 : 2;   // waves along N
    constexpr int TPR = THREADS / 8;                // rows staged per round
    int bx = blockIdx.x, by = blockIdx.y, bz = blockIdx.z;
    if constexpr (SWZ) {
        const int gx = gridDim.x, gy = gridDim.y;
        const int nwg = gx * gy * (int)gridDim.z;
        const int flat = bx + gx * (by + gy * bz);
        const int r = (flat & 7) * (nwg >> 3) + (flat >> 3);
        bx = r % gx; by = (r / gx) % gy; bz = r / (gx * gy);
    }
    const int tid  = threadIdx.x;
    const int lane = tid & 63;
    const int wid  = tid >> 6;
    const int b = bz >> sbits;
    const int s = bz & ((1 << sbits) - 1);
    const int m0 = bx * BM;
    const int ksl = (KSP > 1) ? (by % KSP) : 0;
    const int n0 = (KSP > 1 ? (by / KSP) : by) * BN;
    const int koff = ksl * (K / KSP);
    const int dil = s + 1;
    const int wm0 = (wid / NWN) * (WRM * 16);
    const int wn0 = (wid % NWN) * (WRN * 16);

    __shared__ __align__(16) char lds[2 * (BM + BN) * 128];

    const char* cenB = (const char*)(cenT + (long)b * (CENROWS * 256));
    const char* Xb = nullptr;
    const char* Yb = nullptr;
    if constexpr (!XG) Xb = (const char*)(X + b * xb + (long)s * xs + (long)m0 * ldx + koff);
    if constexpr (!YG) Yb = (const char*)(Y + b * yb + (long)s * ys + (long)n0 * ldy + koff);

    // per-lane gather byte offsets for the current offset index j
    u32 offX[XG ? BM / TPR : 1];
    u32 offY[YG ? BN / TPR : 1];
    auto calcOff = [&](int j) {
        const int dy = (j < 8) ? cOFFY[j] * dil : 0;
        const int dx = (j < 8) ? cOFFX[j] * dil : 0;
        if constexpr (XG) {
            #pragma unroll
            for (int r = 0; r < BM / TPR; r++) {
                const int R = r * TPR + (tid >> 3);
                const int a = m0 + R, yy = (a >> 6) + dy, xx = (a & 63) + dx;
                const int row = (((unsigned)yy < 64u) && ((unsigned)xx < 64u)) ? ((yy << 6) + xx) : 4096;
                offX[r] = ((u32)row << 9) + (((lane & 7) * 16) ^ ((R & 7) << 4));
            }
        }
        if constexpr (YG) {
            #pragma unroll
            for (int r = 0; r < BN / TPR; r++) {
                const int R = r * TPR + (tid >> 3);
                const int a = n0 + R, yy = (a >> 6) + dy, xx = (a & 63) + dx;
                const int row = (((unsigned)yy < 64u) && ((unsigned)xx < 64u)) ? ((yy << 6) + xx) : 4096;
                offY[r] = ((u32)row << 9) + (((lane & 7) * 16) ^ ((R & 7) << 4));
            }
        }
    };

    auto stage = [&](int bf, int t) {
        char* LX = lds + bf * ((BM + BN) * 128);
        char* LY = LX + BM * 128;
        if constexpr (!XG) {
            const char* base = Xb + (long)t * 128;
            #pragma unroll
            for (int r = 0; r < BM / TPR; r++) {
                const int R = r * TPR + (tid >> 3);
                gld16(base + (long)R * (ldx * 2) + (((lane & 7) * 16) ^ ((R & 7) << 4)),
                      LX + (r * TPR + wid * 8) * 128);
            }
        } else {
            const int cb = (t & 3) * 128;
            #pragma unroll
            for (int r = 0; r < BM / TPR; r++)
                gld16(cenB + offX[r] + cb, LX + (r * TPR + wid * 8) * 128);
        }
        if constexpr (!YG) {
            const char* base = Yb + (long)t * 128;
            #pragma unroll
            for (int r = 0; r < BN / TPR; r++) {
                const int R = r * TPR + (tid >> 3);
                gld16(base + (long)R * (ldy * 2) + (((lane & 7) * 16) ^ ((R & 7) << 4)),
                      LY + (r * TPR + wid * 8) * 128);
            }
        } else {
            const int cb = (t & 3) * 128;
            #pragma unroll
            for (int r = 0; r < BN / TPR; r++)
                gld16(cenB + offY[r] + cb, LY + (r * TPR + wid * 8) * 128);
        }
    };

    f32x4 acc[WRM][WRN] = {};

    auto comp = [&](int bf) {
        const char* LX = lds + bf * ((BM + BN) * 128);
        const char* LY = LX + BM * 128;
        #pragma unroll
        for (int kk = 0; kk < 2; kk++) {
            const int kb = kk * 64 + ((lane >> 4) << 4);
            s16x8 af[WRM], bfr[WRN];
            #pragma unroll
            for (int m = 0; m < WRM; m++)
                af[m] = *(const s16x8*)(LX + swz(wm0 + m * 16 + (lane & 15), kb));
            #pragma unroll
            for (int n = 0; n < WRN; n++)
                bfr[n] = *(const s16x8*)(LY + swz(wn0 + n * 16 + (lane & 15), kb));
            #pragma unroll
            for (int m = 0; m < WRM; m++)
                #pragma unroll
                for (int n = 0; n < WRN; n++)
                    acc[m][n] = __builtin_amdgcn_mfma_f32_16x16x32_bf16(af[m], bfr[n], acc[m][n], 0, 0, 0);
        }
    };

    const int nt = (K / KSP) / 64;
    if constexpr (XG || YG) calcOff(0);
    stage(0, 0);
    __syncthreads();
    int cur = 0;
    for (int t = 0; t < nt; t++) {
        if (t + 1 < nt) {
            if constexpr (XG || YG) {
                if (((t + 1) & 3) == 0) calcOff((t + 1) >> 2);
            }
            stage(cur ^ 1, t + 1);
        }
        comp(cur);
        __syncthreads();
        cur ^= 1;
    }

    if constexpr (NRM) {
        const int slot = by * NWN + (wid % NWN);
        #pragma unroll
        for (int m = 0; m < WRM; m++) {
            float ss[4] = {0.f, 0.f, 0.f, 0.f};
            float s1v[4] = {0.f, 0.f, 0.f, 0.f};
            #pragma unroll
            for (int n = 0; n < WRN; n++)
                #pragma unroll
                for (int i = 0; i < 4; i++) {
                    float v = (NRM == 1) ? bf2f(f2bf(acc[m][n][i])) : acc[m][n][i];
                    ss[i] += v * v;
                    if constexpr (NRM == 2) s1v[i] += v;
                }
            #pragma unroll
            for (int o = 1; o < 16; o <<= 1)
                #pragma unroll
                for (int i = 0; i < 4; i++) {
                    ss[i] += __shfl_xor(ss[i], o);
                    if constexpr (NRM == 2) s1v[i] += __shfl_xor(s1v[i], o);
                }
            if ((lane & 15) == 0) {
                const int row0 = m0 + wm0 + m * 16 + ((lane >> 4) << 2);
                #pragma unroll
                for (int i = 0; i < 4; i++) {
                    if constexpr (NRM == 1) {
                        nrm[((long)(b * nb + s * ns + row0 + i) << NSH) + slot] = ss[i];
                    } else {
                        float* p = nrm + ((long)(row0 + i) << 8) + (b << 6) + slot;
                        p[0] = s1v[i];
                        p[65536] = ss[i];
                    }
                }
            }
        }
    }

    // epilogue: D row = (lane>>4)*4 + i, col = lane&15
    #pragma unroll
    for (int m = 0; m < WRM; m++) {
        const int row0 = m0 + wm0 + m * 16 + ((lane >> 4) << 2);
        #pragma unroll
        for (int n = 0; n < WRN; n++) {
            const int col = n0 + wn0 + n * 16 + (lane & 15);
            f32x4 a = acc[m][n];
            if constexpr (DM == 1) {
                float* Dp = (float*)D + (long)ksl * kpl + b * db + (long)s * dsn;
                #pragma unroll
                for (int i = 0; i < 4; i++) Dp[(long)(row0 + i) * ldd + col] = a[i];
            } else {
                u16* Dp = (u16*)D + b * db + (long)s * dsn;
                #pragma unroll
                for (int i = 0; i < 4; i++) Dp[(long)(row0 + i) * ldd + col] = f2bf(a[i]);
            }
        }
    }
}

// ---------------------------------------------------------------------------
// small kernels (r13 split prep — r14's fused prep_all cost ~9us)
// ---------------------------------------------------------------------------
// fused: kw/qw/ow bf16 casts + cenT zero-row init (single lightweight launch)
__global__ void cast_all(const float* __restrict__ kw, const float* __restrict__ qw,
                         const float* __restrict__ ow,
                         u16* __restrict__ KWb, u16* __restrict__ QWb,
                         u16* __restrict__ OWb, u16* __restrict__ cenT) {
    const int i = blockIdx.x * 256 + threadIdx.x;
    const float* src; u16* dst; long o;
    if (i < 524288)      { src = kw; dst = KWb; o = i; }
    else if (i < 532480) { src = qw; dst = QWb; o = i - 524288; }
    else if (i < 540672) { src = ow; dst = OWb; o = i - 532480; }
    else {
        const int t = i - 540672;
        if (t < 512) {
            const int b = t >> 7, w = t & 127;
            ((u32*)(cenT + (long)b * (CENROWS * 256) + 4096L * 256))[w] = 0u;
        }
        return;
    }
    const float* s = src + o * 8;
    u32x4 v;
    #pragma unroll
    for (int j = 0; j < 4; j++) {
        u16 lo = f2bf(s[2 * j]), hi = f2bf(s[2 * j + 1]);
        v[j] = (u32)lo | ((u32)hi << 16);
    }
    *(u32x4*)(dst + o * 8) = v;
}

// transpose+cast: src f32 [z][R][C] -> dst bf16 [z-stride dstride][C][R] * scale
__global__ __launch_bounds__(256) void transpose_cast(const float* __restrict__ src, u16* __restrict__ dst,
                                                      int R, int C, float scale, long dstride) {
    __shared__ float t[64][65];
    const int tx = threadIdx.x & 63, ty = threadIdx.x >> 6;
    const int c0 = blockIdx.x * 64, r0 = blockIdx.y * 64;
    const float* s = src + (long)blockIdx.z * R * C + (long)r0 * C + c0;
    #pragma unroll
    for (int i = 0; i < 16; i++) t[ty + i * 4][tx] = s[(long)(ty + i * 4) * C + tx];
    __syncthreads();
    u16* d = dst + (long)blockIdx.z * dstride + (long)c0 * R + r0;
    #pragma unroll
    for (int i = 0; i < 16; i++) d[(long)(ty + i * 4) * R + tx] = f2bf(t[tx][ty + i * 4] * scale);
}

// per (b,s): reduce norm partials (q:64, k:128 slots), sum 4 split-K score
// planes, scale by 1/(|q||k|), instance-norm over [64][512], row softmax ->
// ws bf16 -> WSWC[...][0:512], wc (sum of 8 chunks) -> [512:576]
__global__ __launch_bounds__(1024) void softmax_in(const float* __restrict__ score,
                                                   const float* __restrict__ nQp,
                                                   const float* __restrict__ nKp,
                                                   u16* __restrict__ wswc) {
    constexpr long PL = 524288;  // split-K plane stride (16*64*512 f32)
    const int bs = blockIdx.x, tid = threadIdx.x;
    const int b = bs >> 2, s = bs & 3;
    const float* S = score + (long)bs * 32768;
    __shared__ float invq[64], invk[512];
    if (tid < 64) {
        const float* p = nQp + ((long)(b * 256 + s * 64 + tid) << 6);
        float a = 0.f;
        #pragma unroll
        for (int j = 0; j < 64; j++) a += p[j];
        invq[tid] = 1.f / fmaxf(sqrtf(a), 1e-12f);
    }
    if (tid < 512) {
        const float* p = nKp + (((long)bs * 512 + tid) << 7);  // 128 slots (8-wave G1)
        float a = 0.f;
        #pragma unroll
        for (int j = 0; j < 128; j++) a += p[j];
        invk[tid] = 1.f / fmaxf(sqrtf(a), 1e-12f);
    }
    __syncthreads();
    auto ldS = [&](int i) -> float {
        return S[i] + S[i + PL] + S[i + 2 * PL] + S[i + 3 * PL];
    };
    float s1 = 0.f, s2 = 0.f;
    for (int i = tid; i < 32768; i += 1024) {
        float v = ldS(i) * invq[i >> 9] * invk[i & 511];
        s1 += v; s2 += v * v;
    }
    __shared__ float ra[1024], rb[1024];
    ra[tid] = s1; rb[tid] = s2; __syncthreads();
    for (int st = 512; st > 0; st >>= 1) {
        if (tid < st) { ra[tid] += ra[tid + st]; rb[tid] += rb[tid + st]; }
        __syncthreads();
    }
    const float mu = ra[0] * (1.f / 32768.f);
    const float var = rb[0] * (1.f / 32768.f) - mu * mu;
    const float rstd = rsqrtf(var + 1e-5f);
    const int wid = tid >> 6, lane = tid & 63;
    u16* W = wswc + (long)bs * 64 * 576;
    for (int r = wid; r < 64; r += 16) {
        float zv[8]; float mx = -3.0e38f;
        const float iq = invq[r];
        #pragma unroll
        for (int i = 0; i < 8; i++) {
            const int c = i * 64 + lane;
            zv[i] = (ldS(r * 512 + c) * iq * invk[c] - mu) * rstd;
            mx = fmaxf(mx, zv[i]);
        }
        #pragma unroll
        for (int o = 32; o > 0; o >>= 1) mx = fmaxf(mx, __shfl_xor(mx, o));
        float sum = 0.f;
        #pragma unroll
        for (int i = 0; i < 8; i++) { zv[i] = __expf(zv[i] - mx); sum += zv[i]; }
        #pragma unroll
        for (int o = 32; o > 0; o >>= 1) sum += __shfl_xor(sum, o);
        const float inv = 1.f / sum;
        float wcv = 0.f;
        #pragma unroll
        for (int i = 0; i < 8; i++) {
            float w = zv[i] * inv; wcv += w;
            W[r * 576 + i * 64 + lane] = f2bf(w);
        }
        W[r * 576 + 512 + lane] = f2bf(wcv);
    }
}

// BN finalize from partials: bnp[c*256 + j] = sum partial, +65536 = sumsq
__global__ __launch_bounds__(256) void bn_finalize(const float* __restrict__ bnp,
                                                   const float* __restrict__ gamma,
                                                   const float* __restrict__ beta,
                                                   float* __restrict__ st) {
    const int c = threadIdx.x;
    const float* p = bnp + ((long)c << 8);
    float s1 = 0.f, s2 = 0.f;
    #pragma unroll 8
    for (int j = 0; j < 256; j++) { s1 += p[j]; s2 += p[65536 + j]; }
    const float mu = s1 * (1.f / 16384.f);
    const float var = s2 * (1.f / 16384.f) - mu * mu;
    const float g = gamma[c] * rsqrtf(var + 1e-5f);
    st[c * 2] = g;
    st[c * 2 + 1] = beta[c] - mu * g;
}

// apply BN+ReLU: out2b bf16 [b][256][4096] -> out f32
__global__ __launch_bounds__(256) void bn_apply(const u16* __restrict__ out2b,
                                                const float* __restrict__ st,
                                                float* __restrict__ out) {
    const long i8 = (long)blockIdx.x * 256 + threadIdx.x;
    const u32x4 v = *(const u32x4*)(out2b + i8 * 8);
    const int c = (int)((i8 * 8) >> 12) & 255;
    const float g = st[c * 2], bt = st[c * 2 + 1];
    float* o = out + i8 * 8;
    #pragma unroll
    for (int j = 0; j < 4; j++) {
        o[2 * j]     = fmaxf(bf2f(v[j] & 0xffff) * g + bt, 0.f);
        o[2 * j + 1] = fmaxf(bf2f(v[j] >> 16) * g + bt, 0.f);
    }
}

// ---------------------------------------------------------------------------
extern "C" void kernel_launch(void* const* d_in, const int* in_sizes, int n_in,
                              void* d_out, int out_size, void* d_ws, size_t ws_size,
                              hipStream_t stream) {
    (void)in_sizes; (void)n_in; (void)out_size; (void)ws_size;
    const float* cen   = (const float*)d_in[0];
    const float* qw    = (const float*)d_in[1];
    const float* lw    = (const float*)d_in[2];
    const float* kw    = (const float*)d_in[3];
    const float* vw    = (const float*)d_in[4];
    const float* ow    = (const float*)d_in[5];
    const float* gamma = (const float*)d_in[6];
    const float* beta  = (const float*)d_in[7];
    float* out = (float*)d_out;

    char* ws = (char*)d_ws;
    size_t off = 0;
    auto alloc = [&](size_t bytes) { size_t o = off; off += (bytes + 255) & ~(size_t)255; return o; };
    u16*   KWb   = (u16*)(ws + alloc(4L * 512 * 2048 * 2));
    u16*   VWt   = (u16*)(ws + alloc(4L * 2048 * 512 * 2));       // vw^T per s
    u16*   QWb   = (u16*)(ws + alloc(256L * 256 * 2));
    u16*   LWt   = (u16*)(ws + alloc(4L * 256 * 64 * 2));         // -lw^T per s
    u16*   OWb   = (u16*)(ws + alloc(256L * 256 * 2));
    u16*   cenT  = (u16*)(ws + alloc(4L * CENROWS * 256 * 2));    // + zero row
    u16*   keys  = (u16*)(ws + alloc(16L * 512 * 4096 * 2));
    u16*   qs    = (u16*)(ws + alloc(16L * 64 * 4096 * 2));
    float* score = (float*)(ws + alloc(4L * 16 * 64 * 512 * 4));  // 4 split-K planes
    u16*   WSWC  = (u16*)(ws + alloc(16L * 64 * 576 * 2));
    u16*   Xcomb = (u16*)(ws + alloc(16L * 64 * 2304 * 2));       // [E | F] per (b,s)
    u16*   out1t = (u16*)(ws + alloc(4L * 4096 * 256 * 2));
    u16*   out2b = (u16*)(ws + alloc(4L * 256 * 4096 * 2));
    float* bnst  = (float*)(ws + alloc(256L * 2 * 4));
    float* nKp   = (float*)(ws + alloc(16L * 512 * 128 * 4));     // key norm partials (128 slots)
    float* nQp   = (float*)(ws + alloc(4L * 256 * 64 * 4));       // q norm partials
    float* bnp   = (float*)(ws + alloc(2L * 65536 * 4));          // BN sum/sumsq partials

    // prep (r13 split form): casts + zero row; transposes.
    cast_all<<<dim3(2115), 256, 0, stream>>>(kw, qw, ow, KWb, QWb, OWb, cenT);
    transpose_cast<<<dim3(32, 8, 4), 256, 0, stream>>>(vw, VWt, 512, 2048, 1.f, 512L * 2048);
    transpose_cast<<<dim3(4, 1, 4),  256, 0, stream>>>(lw, LWt, 64, 256, -1.f, 64L * 256);
    transpose_cast<<<dim3(64, 4, 4), 256, 0, stream>>>(cen, cenT, 256, 4096, 1.f, (long)CENROWS * 256);

    // G1 keys[bs][512][4096] = KW[s] · surr_t(b,s)^T (Y gathered) + norm partials
    // 512-thr 8-wave blocks (2Mx4N), 128^2 tile, 64KiB LDS (r14-proven, 905 TF)
    gemm_tn<128,128,4,2, 0,1, 0, 1, 1, 1, 512, 7><<<dim3(4, 32, 16), 512, 0, stream>>>(
        KWb, nullptr, keys, cenT, nKp,
        2048, 2048, 0, 4096, 2,
        0L, 512L * 2048, 0L, 0L, 4L * 512 * 4096, 512L * 4096, 2048L, 512L, 0L);
    // G3 qs[b][256][4096] = QW_all · cen_t[b]^T + q norm partials (64x128 tiles)
    gemm_tn<64,128,2,4, 0,0, 0, 1, 1, 0, 256, 6><<<dim3(4, 32, 4), 256, 0, stream>>>(
        QWb, cenT, qs, cenT, nQp,
        256, 256, 256, 4096, 0,
        0L, 0L, (long)CENROWS * 256, 0L, 256L * 4096, 0L, 256L, 0L, 0L);
    // G5 raw score planes: score[ksl][bs][64][512] = qs · keys^T over k-slice
    gemm_tn<64,64,2,2, 0,0, 1, 0, 4, 0, 256, 6><<<dim3(1, 32, 16), 256, 0, stream>>>(
        qs, keys, score, cenT, nullptr,
        4096, 4096, 4096, 512, 2,
        256L * 4096, 64L * 4096, 4L * 512 * 4096, 512L * 4096, 4L * 64 * 512, 64L * 512,
        0L, 0L, 524288L);
    // norm-reduce + plane-sum + scale + instance-norm + softmax (+ wc)
    softmax_in<<<dim3(16), 1024, 0, stream>>>(score, nQp, nKp, WSWC);

    // E: Xcomb[bs][64][0:2048] = ws · VW[s]   (ws rows in WSWC, stride 576)
    gemm_tn<64,128,2,4, 0,0, 0, 0, 1, 0, 256, 6><<<dim3(1, 16, 16), 256, 0, stream>>>(
        WSWC, VWt, Xcomb, cenT, nullptr,
        512, 576, 512, 2304, 2,
        4L * 64 * 576, 64L * 576, 0L, 2048L * 512, 4L * 64 * 2304, 64L * 2304, 0L, 0L, 0L);
    // F: Xcomb[bs][64][2048:2304] = wc · (-LW[s])  (wc at WSWC col 512)
    gemm_tn<64,128,2,4, 0,0, 0, 0, 1, 0, 256, 6><<<dim3(1, 2, 16), 256, 0, stream>>>(
        WSWC + 512, LWt, Xcomb + 2048, cenT, nullptr,
        64, 576, 64, 2304, 2,
        4L * 64 * 576, 64L * 576, 0L, 256L * 64, 4L * 64 * 2304, 64L * 2304, 0L, 0L, 0L);
    // G6n out1_t[b][4096][s*64+h] = [surr_t | cen_t] · Xcomb[bs]^T  (K=2304,
    // X gathered: k<2048 shifted, k>=2048 center) + T1 swizzle (512 = 8 x 64)
    gemm_tn<128,64,4,2, 1,0, 0, 0, 1, 1, 256, 6><<<dim3(32, 1, 16), 256, 0, stream>>>(
        nullptr, Xcomb, out1t, cenT, nullptr,
        2304, 0, 2304, 256, 2,
        0L, 0L, 4L * 64 * 2304, 64L * 2304, 4096L * 256, 64L, 0L, 0L, 0L);

    // G7 out2b[b][256][4096] (bf16) = OW · out1_t[b]^T + BN stat partials
    gemm_tn<64,128,2,4, 0,0, 0, 2, 1, 0, 256, 6><<<dim3(4, 32, 4), 256, 0, stream>>>(
        OWb, out1t, out2b, cenT, bnp,
        256, 256, 256, 4096, 0,
        0L, 0L, 4096L * 256, 0L, 256L * 4096, 0L, 0L, 0L, 0L);

    bn_finalize<<<dim3(1), 256, 0, stream>>>(bnp, gamma, beta, bnst);
    bn_apply<<<dim3(2048), 256, 0, stream>>>(out2b, bnst, out);
}

// Round 16
// 280.368 us; speedup vs baseline: 1.0211x; 1.0211x over previous
//
#include <hip/hip_runtime.h>

// ExpansionContrastModule on MI355X (gfx950), bf16 MFMA pipeline.
// FINAL CONFIG (= r14, best measured 280.7us; r15's split-prep revert was
// chasing cross-run noise — rule #13 — and regressed to 286.3).
// R7 associativity: out = (ws·VW)·surr - (wc·LW)·cen (deletes 137-GF vals GEMM).
// R9 determinism: no atomics; single-writer partial slots everywhere.
// R10: G5 split-K x4 planes. R11: T1 XCD swizzle on G1/G6n. R12: gather
// address hoisting. R13: G3/G7 64x128 retile, 1024-thr softmax.
// R14: G1 512-thr 8-wave blocks (2Mx4N, 16 waves/CU) -> 905 TF = 99% of the
// verified plain-HIP 2-phase structure ceiling (m97: 912 TF); fused prep.

typedef unsigned short u16;
typedef unsigned int u32;
typedef __attribute__((ext_vector_type(4))) unsigned int u32x4;
typedef __attribute__((ext_vector_type(8))) short s16x8;
typedef __attribute__((ext_vector_type(4))) float f32x4;

#define DEVFN static __device__ __forceinline__

DEVFN u16 f2bf(float f) {
    u32 u = __builtin_bit_cast(u32, f);
    u32 r = (u + 0x7fffu + ((u >> 16) & 1u)) >> 16;  // RNE
    return (u16)r;
}
DEVFN float bf2f(u32 h) { u32 u = h << 16; return __builtin_bit_cast(float, u); }

typedef __attribute__((address_space(1))) const unsigned int gu32;
typedef __attribute__((address_space(3))) unsigned int lu32;
DEVFN void gld16(const void* g, void* l) {
    __builtin_amdgcn_global_load_lds((gu32*)g, (lu32*)l, 16, 0, 0);
}

// OFFSETS = [(-1,-1),(-1,0),(-1,1),(0,1),(1,1),(1,0),(1,-1),(0,-1)]
__constant__ int cOFFY[8] = {-1,-1,-1, 0, 1, 1, 1, 0};
__constant__ int cOFFX[8] = {-1, 0, 1, 1, 1, 0,-1,-1};

// cenT row stride (4096 area rows + 1 zero row) in u16 elements
#define CENROWS 4097

// XOR swizzle within a 128B LDS row (BK=64 bf16): measured 0 conflicts (r1-r15).
DEVFN int swz(int r, int kb) { return r * 128 + (kb ^ ((r & 7) << 4)); }

// ---------------------------------------------------------------------------
// 2-phase TN GEMM. BK=64. THREADS=256 (4 waves, 2x2) or 512 (8 waves, 2x4).
// LDS = 2*(BM+BN)*128 B.
// XG/YG: operand gathered from cen_t; k<2048 -> offset j=k>>8 shifted by
// dilation, k>=2048 -> unshifted rows. Offsets precomputed per j (every 4
// K-tiles) into statically indexed registers; OOB -> cenT zero row (4096).
// DM: 0 = bf16 out, 1 = f32 out (plane ksl*kpl when KSP>1).
// NRM (deterministic single-writer partials):
//  1 = per-row ||row||^2 (bf16-rounded) -> nrm[(rowid<<NSH) + by*NWN + widN]
//  2 = per-row (sum,sumsq) -> nrm[row*256 + b*64 + by*2 + (wid&1)], +65536.
// KSP: split-K count; by = ytile*KSP + kslice; deterministic output planes.
// SWZ: T1 XCD-chunked remap (requires nwg % 8 == 0).
// ---------------------------------------------------------------------------
template<int BM, int BN, int WRM, int WRN, int XG, int YG, int DM, int NRM,
         int KSP, int SWZ, int THREADS, int NSH>
__global__ __launch_bounds__(THREADS, (THREADS == 512 ? 4 : 2))
void gemm_tn(const u16* __restrict__ X, const u16* __restrict__ Y,
             void* __restrict__ D, const u16* __restrict__ cenT,
             float* __restrict__ nrm,
             int K, int ldx, int ldy, int ldd, int sbits,
             long xb, long xs, long yb, long ys, long db, long dsn,
             long nb, long ns, long kpl)
{
    static_assert(KSP == 1 || (!XG && !YG), "split-K only for non-gather");
    constexpr int NWN = (THREADS == 512) ? 4 : 2;   // waves along N
    constexpr int TPR = THREADS / 8;                // rows staged per round
    int bx = blockIdx.x, by = blockIdx.y, bz = blockIdx.z;
    if constexpr (SWZ) {
        const int gx = gridDim.x, gy = gridDim.y;
        const int nwg = gx * gy * (int)gridDim.z;
        const int flat = bx + gx * (by + gy * bz);
        const int r = (flat & 7) * (nwg >> 3) + (flat >> 3);
        bx = r % gx; by = (r / gx) % gy; bz = r / (gx * gy);
    }
    const int tid  = threadIdx.x;
    const int lane = tid & 63;
    const int wid  = tid >> 6;
    const int b = bz >> sbits;
    const int s = bz & ((1 << sbits) - 1);
    const int m0 = bx * BM;
    const int ksl = (KSP > 1) ? (by % KSP) : 0;
    const int n0 = (KSP > 1 ? (by / KSP) : by) * BN;
    const int koff = ksl * (K / KSP);
    const int dil = s + 1;
    const int wm0 = (wid / NWN) * (WRM * 16);
    const int wn0 = (wid % NWN) * (WRN * 16);

    __shared__ __align__(16) char lds[2 * (BM + BN) * 128];

    const char* cenB = (const char*)(cenT + (long)b * (CENROWS * 256));
    const char* Xb = nullptr;
    const char* Yb = nullptr;
    if constexpr (!XG) Xb = (const char*)(X + b * xb + (long)s * xs + (long)m0 * ldx + koff);
    if constexpr (!YG) Yb = (const char*)(Y + b * yb + (long)s * ys + (long)n0 * ldy + koff);

    // per-lane gather byte offsets for the current offset index j
    u32 offX[XG ? BM / TPR : 1];
    u32 offY[YG ? BN / TPR : 1];
    auto calcOff = [&](int j) {
        const int dy = (j < 8) ? cOFFY[j] * dil : 0;
        const int dx = (j < 8) ? cOFFX[j] * dil : 0;
        if constexpr (XG) {
            #pragma unroll
            for (int r = 0; r < BM / TPR; r++) {
                const int R = r * TPR + (tid >> 3);
                const int a = m0 + R, yy = (a >> 6) + dy, xx = (a & 63) + dx;
                const int row = (((unsigned)yy < 64u) && ((unsigned)xx < 64u)) ? ((yy << 6) + xx) : 4096;
                offX[r] = ((u32)row << 9) + (((lane & 7) * 16) ^ ((R & 7) << 4));
            }
        }
        if constexpr (YG) {
            #pragma unroll
            for (int r = 0; r < BN / TPR; r++) {
                const int R = r * TPR + (tid >> 3);
                const int a = n0 + R, yy = (a >> 6) + dy, xx = (a & 63) + dx;
                const int row = (((unsigned)yy < 64u) && ((unsigned)xx < 64u)) ? ((yy << 6) + xx) : 4096;
                offY[r] = ((u32)row << 9) + (((lane & 7) * 16) ^ ((R & 7) << 4));
            }
        }
    };

    auto stage = [&](int bf, int t) {
        char* LX = lds + bf * ((BM + BN) * 128);
        char* LY = LX + BM * 128;
        if constexpr (!XG) {
            const char* base = Xb + (long)t * 128;
            #pragma unroll
            for (int r = 0; r < BM / TPR; r++) {
                const int R = r * TPR + (tid >> 3);
                gld16(base + (long)R * (ldx * 2) + (((lane & 7) * 16) ^ ((R & 7) << 4)),
                      LX + (r * TPR + wid * 8) * 128);
            }
        } else {
            const int cb = (t & 3) * 128;
            #pragma unroll
            for (int r = 0; r < BM / TPR; r++)
                gld16(cenB + offX[r] + cb, LX + (r * TPR + wid * 8) * 128);
        }
        if constexpr (!YG) {
            const char* base = Yb + (long)t * 128;
            #pragma unroll
            for (int r = 0; r < BN / TPR; r++) {
                const int R = r * TPR + (tid >> 3);
                gld16(base + (long)R * (ldy * 2) + (((lane & 7) * 16) ^ ((R & 7) << 4)),
                      LY + (r * TPR + wid * 8) * 128);
            }
        } else {
            const int cb = (t & 3) * 128;
            #pragma unroll
            for (int r = 0; r < BN / TPR; r++)
                gld16(cenB + offY[r] + cb, LY + (r * TPR + wid * 8) * 128);
        }
    };

    f32x4 acc[WRM][WRN] = {};

    auto comp = [&](int bf) {
        const char* LX = lds + bf * ((BM + BN) * 128);
        const char* LY = LX + BM * 128;
        #pragma unroll
        for (int kk = 0; kk < 2; kk++) {
            const int kb = kk * 64 + ((lane >> 4) << 4);
            s16x8 af[WRM], bfr[WRN];
            #pragma unroll
            for (int m = 0; m < WRM; m++)
                af[m] = *(const s16x8*)(LX + swz(wm0 + m * 16 + (lane & 15), kb));
            #pragma unroll
            for (int n = 0; n < WRN; n++)
                bfr[n] = *(const s16x8*)(LY + swz(wn0 + n * 16 + (lane & 15), kb));
            #pragma unroll
            for (int m = 0; m < WRM; m++)
                #pragma unroll
                for (int n = 0; n < WRN; n++)
                    acc[m][n] = __builtin_amdgcn_mfma_f32_16x16x32_bf16(af[m], bfr[n], acc[m][n], 0, 0, 0);
        }
    };

    const int nt = (K / KSP) / 64;
    if constexpr (XG || YG) calcOff(0);
    stage(0, 0);
    __syncthreads();
    int cur = 0;
    for (int t = 0; t < nt; t++) {
        if (t + 1 < nt) {
            if constexpr (XG || YG) {
                if (((t + 1) & 3) == 0) calcOff((t + 1) >> 2);
            }
            stage(cur ^ 1, t + 1);
        }
        comp(cur);
        __syncthreads();
        cur ^= 1;
    }

    if constexpr (NRM) {
        const int slot = by * NWN + (wid % NWN);
        #pragma unroll
        for (int m = 0; m < WRM; m++) {
            float ss[4] = {0.f, 0.f, 0.f, 0.f};
            float s1v[4] = {0.f, 0.f, 0.f, 0.f};
            #pragma unroll
            for (int n = 0; n < WRN; n++)
                #pragma unroll
                for (int i = 0; i < 4; i++) {
                    float v = (NRM == 1) ? bf2f(f2bf(acc[m][n][i])) : acc[m][n][i];
                    ss[i] += v * v;
                    if constexpr (NRM == 2) s1v[i] += v;
                }
            #pragma unroll
            for (int o = 1; o < 16; o <<= 1)
                #pragma unroll
                for (int i = 0; i < 4; i++) {
                    ss[i] += __shfl_xor(ss[i], o);
                    if constexpr (NRM == 2) s1v[i] += __shfl_xor(s1v[i], o);
                }
            if ((lane & 15) == 0) {
                const int row0 = m0 + wm0 + m * 16 + ((lane >> 4) << 2);
                #pragma unroll
                for (int i = 0; i < 4; i++) {
                    if constexpr (NRM == 1) {
                        nrm[((long)(b * nb + s * ns + row0 + i) << NSH) + slot] = ss[i];
                    } else {
                        float* p = nrm + ((long)(row0 + i) << 8) + (b << 6) + slot;
                        p[0] = s1v[i];
                        p[65536] = ss[i];
                    }
                }
            }
        }
    }

    // epilogue: D row = (lane>>4)*4 + i, col = lane&15
    #pragma unroll
    for (int m = 0; m < WRM; m++) {
        const int row0 = m0 + wm0 + m * 16 + ((lane >> 4) << 2);
        #pragma unroll
        for (int n = 0; n < WRN; n++) {
            const int col = n0 + wn0 + n * 16 + (lane & 15);
            f32x4 a = acc[m][n];
            if constexpr (DM == 1) {
                float* Dp = (float*)D + (long)ksl * kpl + b * db + (long)s * dsn;
                #pragma unroll
                for (int i = 0; i < 4; i++) Dp[(long)(row0 + i) * ldd + col] = a[i];
            } else {
                u16* Dp = (u16*)D + b * db + (long)s * dsn;
                #pragma unroll
                for (int i = 0; i < 4; i++) Dp[(long)(row0 + i) * ldd + col] = f2bf(a[i]);
            }
        }
    }
}

// ---------------------------------------------------------------------------
// fused prep: all weight casts, all transposes, cenT zero-row (one launch)
// block ranges: [0,2048) kw cast | [2048,2080) qw | [2080,2112) ow |
// [2112,3136) vw transpose | [3136,3152) lw transpose | [3152,4176) cen
// transpose | [4176] zero rows.
// ---------------------------------------------------------------------------
__global__ __launch_bounds__(256) void prep_all(
    const float* __restrict__ kw, const float* __restrict__ qw,
    const float* __restrict__ ow, const float* __restrict__ vw,
    const float* __restrict__ lw, const float* __restrict__ cen,
    u16* __restrict__ KWb, u16* __restrict__ QWb, u16* __restrict__ OWb,
    u16* __restrict__ VWt, u16* __restrict__ LWt, u16* __restrict__ cenT)
{
    const int bid = blockIdx.x;
    const int tid = threadIdx.x;
    __shared__ float t[64][65];

    if (bid < 2112) {  // vectorized casts, 8 f32 -> 8 bf16 per thread
        const float* src; u16* dst; long o;
        const long i = (long)bid * 256 + tid;
        if (bid < 2048)      { src = kw; dst = KWb; o = i; }
        else if (bid < 2080) { src = qw; dst = QWb; o = i - 2048L * 256; }
        else                 { src = ow; dst = OWb; o = i - 2080L * 256; }
        const float* s = src + o * 8;
        u32x4 v;
        #pragma unroll
        for (int j = 0; j < 4; j++) {
            u16 lo = f2bf(s[2 * j]), hi = f2bf(s[2 * j + 1]);
            v[j] = (u32)lo | ((u32)hi << 16);
        }
        *(u32x4*)(dst + o * 8) = v;
        return;
    }
    if (bid == 4176) {  // cenT OOB zero rows: 4 b x 128 u32
        if (tid < 128)
            #pragma unroll
            for (int b2 = 0; b2 < 4; b2++)
                ((u32*)(cenT + (long)b2 * (CENROWS * 256) + 4096L * 256))[tid] = 0u;
        return;
    }
    // transpose jobs: 64x64 f32 tile -> bf16 transposed * scale
    const float* src; u16* dst; int R, C; float scale; long dstride;
    int cx, ry, z;
    int tb = bid - 2112;
    if (tb < 1024) {          // vw [4][512][2048] -> VWt [4][2048][512]
        src = vw; dst = VWt; R = 512; C = 2048; scale = 1.f; dstride = 512L * 2048;
        cx = tb & 31; ry = (tb >> 5) & 7; z = tb >> 8;
    } else if (tb < 1040) {   // lw [4][64][256] -> LWt * (-1)
        tb -= 1024;
        src = lw; dst = LWt; R = 64; C = 256; scale = -1.f; dstride = 64L * 256;
        cx = tb & 3; ry = 0; z = tb >> 2;
    } else {                  // cen [4][256][4096] -> cenT (stride CENROWS*256)
        tb -= 1040;
        src = cen; dst = cenT; R = 256; C = 4096; scale = 1.f; dstride = (long)CENROWS * 256;
        cx = tb & 63; ry = (tb >> 6) & 3; z = tb >> 8;
    }
    const int tx = tid & 63, ty = tid >> 6;
    const int c0 = cx * 64, r0 = ry * 64;
    const float* sp = src + (long)z * R * C + (long)r0 * C + c0;
    #pragma unroll
    for (int i = 0; i < 16; i++) t[ty + i * 4][tx] = sp[(long)(ty + i * 4) * C + tx];
    __syncthreads();
    u16* d = dst + (long)z * dstride + (long)c0 * R + r0;
    #pragma unroll
    for (int i = 0; i < 16; i++) d[(long)(ty + i * 4) * R + tx] = f2bf(t[tx][ty + i * 4] * scale);
}

// per (b,s): reduce norm partials (q:64, k:128 slots), sum 4 split-K score
// planes, scale by 1/(|q||k|), instance-norm over [64][512], row softmax ->
// ws bf16 -> WSWC[...][0:512], wc (sum of 8 chunks) -> [512:576]
__global__ __launch_bounds__(1024) void softmax_in(const float* __restrict__ score,
                                                   const float* __restrict__ nQp,
                                                   const float* __restrict__ nKp,
                                                   u16* __restrict__ wswc) {
    constexpr long PL = 524288;  // split-K plane stride (16*64*512 f32)
    const int bs = blockIdx.x, tid = threadIdx.x;
    const int b = bs >> 2, s = bs & 3;
    const float* S = score + (long)bs * 32768;
    __shared__ float invq[64], invk[512];
    if (tid < 64) {
        const float* p = nQp + ((long)(b * 256 + s * 64 + tid) << 6);
        float a = 0.f;
        #pragma unroll
        for (int j = 0; j < 64; j++) a += p[j];
        invq[tid] = 1.f / fmaxf(sqrtf(a), 1e-12f);
    }
    if (tid < 512) {
        const float* p = nKp + (((long)bs * 512 + tid) << 7);  // 128 slots (8-wave G1)
        float a = 0.f;
        #pragma unroll
        for (int j = 0; j < 128; j++) a += p[j];
        invk[tid] = 1.f / fmaxf(sqrtf(a), 1e-12f);
    }
    __syncthreads();
    auto ldS = [&](int i) -> float {
        return S[i] + S[i + PL] + S[i + 2 * PL] + S[i + 3 * PL];
    };
    float s1 = 0.f, s2 = 0.f;
    for (int i = tid; i < 32768; i += 1024) {
        float v = ldS(i) * invq[i >> 9] * invk[i & 511];
        s1 += v; s2 += v * v;
    }
    __shared__ float ra[1024], rb[1024];
    ra[tid] = s1; rb[tid] = s2; __syncthreads();
    for (int st = 512; st > 0; st >>= 1) {
        if (tid < st) { ra[tid] += ra[tid + st]; rb[tid] += rb[tid + st]; }
        __syncthreads();
    }
    const float mu = ra[0] * (1.f / 32768.f);
    const float var = rb[0] * (1.f / 32768.f) - mu * mu;
    const float rstd = rsqrtf(var + 1e-5f);
    const int wid = tid >> 6, lane = tid & 63;
    u16* W = wswc + (long)bs * 64 * 576;
    for (int r = wid; r < 64; r += 16) {
        float zv[8]; float mx = -3.0e38f;
        const float iq = invq[r];
        #pragma unroll
        for (int i = 0; i < 8; i++) {
            const int c = i * 64 + lane;
            zv[i] = (ldS(r * 512 + c) * iq * invk[c] - mu) * rstd;
            mx = fmaxf(mx, zv[i]);
        }
        #pragma unroll
        for (int o = 32; o > 0; o >>= 1) mx = fmaxf(mx, __shfl_xor(mx, o));
        float sum = 0.f;
        #pragma unroll
        for (int i = 0; i < 8; i++) { zv[i] = __expf(zv[i] - mx); sum += zv[i]; }
        #pragma unroll
        for (int o = 32; o > 0; o >>= 1) sum += __shfl_xor(sum, o);
        const float inv = 1.f / sum;
        float wcv = 0.f;
        #pragma unroll
        for (int i = 0; i < 8; i++) {
            float w = zv[i] * inv; wcv += w;
            W[r * 576 + i * 64 + lane] = f2bf(w);
        }
        W[r * 576 + 512 + lane] = f2bf(wcv);
    }
}

// BN finalize from partials: bnp[c*256 + j] = sum partial, +65536 = sumsq
__global__ __launch_bounds__(256) void bn_finalize(const float* __restrict__ bnp,
                                                   const float* __restrict__ gamma,
                                                   const float* __restrict__ beta,
                                                   float* __restrict__ st) {
    const int c = threadIdx.x;
    const float* p = bnp + ((long)c << 8);
    float s1 = 0.f, s2 = 0.f;
    #pragma unroll 8
    for (int j = 0; j < 256; j++) { s1 += p[j]; s2 += p[65536 + j]; }
    const float mu = s1 * (1.f / 16384.f);
    const float var = s2 * (1.f / 16384.f) - mu * mu;
    const float g = gamma[c] * rsqrtf(var + 1e-5f);
    st[c * 2] = g;
    st[c * 2 + 1] = beta[c] - mu * g;
}

// apply BN+ReLU: out2b bf16 [b][256][4096] -> out f32
__global__ __launch_bounds__(256) void bn_apply(const u16* __restrict__ out2b,
                                                const float* __restrict__ st,
                                                float* __restrict__ out) {
    const long i8 = (long)blockIdx.x * 256 + threadIdx.x;
    const u32x4 v = *(const u32x4*)(out2b + i8 * 8);
    const int c = (int)((i8 * 8) >> 12) & 255;
    const float g = st[c * 2], bt = st[c * 2 + 1];
    float* o = out + i8 * 8;
    #pragma unroll
    for (int j = 0; j < 4; j++) {
        o[2 * j]     = fmaxf(bf2f(v[j] & 0xffff) * g + bt, 0.f);
        o[2 * j + 1] = fmaxf(bf2f(v[j] >> 16) * g + bt, 0.f);
    }
}

// ---------------------------------------------------------------------------
extern "C" void kernel_launch(void* const* d_in, const int* in_sizes, int n_in,
                              void* d_out, int out_size, void* d_ws, size_t ws_size,
                              hipStream_t stream) {
    (void)in_sizes; (void)n_in; (void)out_size; (void)ws_size;
    const float* cen   = (const float*)d_in[0];
    const float* qw    = (const float*)d_in[1];
    const float* lw    = (const float*)d_in[2];
    const float* kw    = (const float*)d_in[3];
    const float* vw    = (const float*)d_in[4];
    const float* ow    = (const float*)d_in[5];
    const float* gamma = (const float*)d_in[6];
    const float* beta  = (const float*)d_in[7];
    float* out = (float*)d_out;

    char* ws = (char*)d_ws;
    size_t off = 0;
    auto alloc = [&](size_t bytes) { size_t o = off; off += (bytes + 255) & ~(size_t)255; return o; };
    u16*   KWb   = (u16*)(ws + alloc(4L * 512 * 2048 * 2));
    u16*   VWt   = (u16*)(ws + alloc(4L * 2048 * 512 * 2));       // vw^T per s
    u16*   QWb   = (u16*)(ws + alloc(256L * 256 * 2));
    u16*   LWt   = (u16*)(ws + alloc(4L * 256 * 64 * 2));         // -lw^T per s
    u16*   OWb   = (u16*)(ws + alloc(256L * 256 * 2));
    u16*   cenT  = (u16*)(ws + alloc(4L * CENROWS * 256 * 2));    // + zero row
    u16*   keys  = (u16*)(ws + alloc(16L * 512 * 4096 * 2));
    u16*   qs    = (u16*)(ws + alloc(16L * 64 * 4096 * 2));
    float* score = (float*)(ws + alloc(4L * 16 * 64 * 512 * 4));  // 4 split-K planes
    u16*   WSWC  = (u16*)(ws + alloc(16L * 64 * 576 * 2));
    u16*   Xcomb = (u16*)(ws + alloc(16L * 64 * 2304 * 2));       // [E | F] per (b,s)
    u16*   out1t = (u16*)(ws + alloc(4L * 4096 * 256 * 2));
    u16*   out2b = (u16*)(ws + alloc(4L * 256 * 4096 * 2));
    float* bnst  = (float*)(ws + alloc(256L * 2 * 4));
    float* nKp   = (float*)(ws + alloc(16L * 512 * 128 * 4));     // key norm partials (128 slots)
    float* nQp   = (float*)(ws + alloc(4L * 256 * 64 * 4));       // q norm partials
    float* bnp   = (float*)(ws + alloc(2L * 65536 * 4));          // BN sum/sumsq partials

    // fused prep (casts + transposes + zero row), one launch
    prep_all<<<dim3(4177), 256, 0, stream>>>(kw, qw, ow, vw, lw, cen,
                                             KWb, QWb, OWb, VWt, LWt, cenT);

    // G1 keys[bs][512][4096] = KW[s] · surr_t(b,s)^T (Y gathered) + norm partials
    // 512-thr 8-wave blocks (2Mx4N), 128^2 tile, 64KiB LDS (905 TF)
    gemm_tn<128,128,4,2, 0,1, 0, 1, 1, 1, 512, 7><<<dim3(4, 32, 16), 512, 0, stream>>>(
        KWb, nullptr, keys, cenT, nKp,
        2048, 2048, 0, 4096, 2,
        0L, 512L * 2048, 0L, 0L, 4L * 512 * 4096, 512L * 4096, 2048L, 512L, 0L);
    // G3 qs[b][256][4096] = QW_all · cen_t[b]^T + q norm partials (64x128 tiles)
    gemm_tn<64,128,2,4, 0,0, 0, 1, 1, 0, 256, 6><<<dim3(4, 32, 4), 256, 0, stream>>>(
        QWb, cenT, qs, cenT, nQp,
        256, 256, 256, 4096, 0,
        0L, 0L, (long)CENROWS * 256, 0L, 256L * 4096, 0L, 256L, 0L, 0L);
    // G5 raw score planes: score[ksl][bs][64][512] = qs · keys^T over k-slice
    gemm_tn<64,64,2,2, 0,0, 1, 0, 4, 0, 256, 6><<<dim3(1, 32, 16), 256, 0, stream>>>(
        qs, keys, score, cenT, nullptr,
        4096, 4096, 4096, 512, 2,
        256L * 4096, 64L * 4096, 4L * 512 * 4096, 512L * 4096, 4L * 64 * 512, 64L * 512,
        0L, 0L, 524288L);
    // norm-reduce + plane-sum + scale + instance-norm + softmax (+ wc)
    softmax_in<<<dim3(16), 1024, 0, stream>>>(score, nQp, nKp, WSWC);

    // E: Xcomb[bs][64][0:2048] = ws · VW[s]   (ws rows in WSWC, stride 576)
    gemm_tn<64,128,2,4, 0,0, 0, 0, 1, 0, 256, 6><<<dim3(1, 16, 16), 256, 0, stream>>>(
        WSWC, VWt, Xcomb, cenT, nullptr,
        512, 576, 512, 2304, 2,
        4L * 64 * 576, 64L * 576, 0L, 2048L * 512, 4L * 64 * 2304, 64L * 2304, 0L, 0L, 0L);
    // F: Xcomb[bs][64][2048:2304] = wc · (-LW[s])  (wc at WSWC col 512)
    gemm_tn<64,128,2,4, 0,0, 0, 0, 1, 0, 256, 6><<<dim3(1, 2, 16), 256, 0, stream>>>(
        WSWC + 512, LWt, Xcomb + 2048, cenT, nullptr,
        64, 576, 64, 2304, 2,
        4L * 64 * 576, 64L * 576, 0L, 256L * 64, 4L * 64 * 2304, 64L * 2304, 0L, 0L, 0L);
    // G6n out1_t[b][4096][s*64+h] = [surr_t | cen_t] · Xcomb[bs]^T  (K=2304,
    // X gathered: k<2048 shifted, k>=2048 center) + T1 swizzle (512 = 8 x 64)
    gemm_tn<128,64,4,2, 1,0, 0, 0, 1, 1, 256, 6><<<dim3(32, 1, 16), 256, 0, stream>>>(
        nullptr, Xcomb, out1t, cenT, nullptr,
        2304, 0, 2304, 256, 2,
        0L, 0L, 4L * 64 * 2304, 64L * 2304, 4096L * 256, 64L, 0L, 0L, 0L);

    // G7 out2b[b][256][4096] (bf16) = OW · out1_t[b]^T + BN stat partials
    gemm_tn<64,128,2,4, 0,0, 0, 2, 1, 0, 256, 6><<<dim3(4, 32, 4), 256, 0, stream>>>(
        OWb, out1t, out2b, cenT, bnp,
        256, 256, 256, 4096, 0,
        0L, 0L, 4096L * 256, 0L, 256L * 4096, 0L, 0L, 0L, 0L);

    bn_finalize<<<dim3(1), 256, 0, stream>>>(bnp, gamma, beta, bnst);
    bn_apply<<<dim3(2048), 256, 0, stream>>>(out2b, bnst, out);
}